// Round 1
// 492.058 us; speedup vs baseline: 1.2189x; 1.2189x over previous
//
#include <hip/hip_runtime.h>

// Greedy NMS: keep[i] = !any(keep[j] for j in knn[i] if j < i)
//
// Round-13 (this session): attack per-hop serial latency. R12 macro-structure
// (74 x 2048 chunks, WCH=4, one forced reload) kept, with:
//   - IN-BAND VALID BITS: keep masks published as u64 words (32 rows in low
//     bits, bit32 = valid). Consumers spin on the data words directly ->
//     detection and fetch merge into ONE LLC round-trip; producer needs no
//     release drain (fire-and-forget relaxed stores). progress counter kept
//     only as the phase-1 trigger hint; per-word valid-spin is the backstop.
//     init kernel zeroes the word region each call (stale valid bits!).
//   - ONE barrier per fixed-point iteration (double-flag protocol: t0
//     pre-zeroes flags[(it+1)&1] during iteration it), 3 monotone sweeps/iter.
//   - il-lists read back into REGISTERS pre-wait (thread wrote them itself;
//     full unroll, compile-time indices -> VGPRs): sweeps do single-level
//     st[reg] LDS reads instead of st[il[x][o]] dependent chains.
//   - window probes unrolled to ECAP with predication, no break: all exl/lm
//     loads pipeline (~2 LDS RTs) instead of up to 12 serial dependent RTs.
//
// Output encoding (validated round 4): INT32.
//   d_out[0..M)        : kept flags, 1 / 0
//   d_out[M..M+M*64)   : kept_knn, idx or 150000 (tail doubles as u64 word
//                        scratch, owned by block 73 which never publishes)
// d_ws[0..3]: progress counter (zeroed by init kernel each call)

#define M_ROWS 150000
#define KNN    64
#define BLK    1024
#define QRT    2
#define CHUNK  (BLK * QRT)                        // 2048
#define NCH    ((M_ROWS + CHUNK - 1) / CHUNK)     // 74
#define ICAP   6
#define ECAP   12
#define WCH    4                                  // exl window, chunks
#define W64PC  (CHUNK / 32)                       // 64 published u64 words/chunk
#define LMW    (((NCH - 1) * CHUNK) / 32)         // 4672 u32 mirror words
#define NBMG   ((NCH - 1) * W64PC)                // 4672 published u64 words
#define OUT_INTS (M_ROWS + M_ROWS * KNN)
#define BMG_INT_OFF (OUT_INTS - NBMG * 2)         // 8B-aligned; rows >= 149854
#define VALIDB (1ull << 32)

__global__ void init_ws_kernel(unsigned int* progress, int* out) {
  const int i = blockIdx.x * blockDim.x + threadIdx.x;
  unsigned long long* bmg64 = (unsigned long long*)(out + BMG_INT_OFF);
  if (i < NBMG) bmg64[i] = 0ull;                  // clear stale valid bits
  if (i == 0) *progress = 0u;
}

// reload a row and probe preds j in [lo, hi) against the LDS bitmask
__device__ __forceinline__ bool probe_reload(const int* __restrict__ rp,
                                             const unsigned int* lm,
                                             int lo, int hi) {
  bool s = false;
#pragma unroll
  for (int u = 0; u < 16; ++u) {
    int4 d = ((const int4*)rp)[u];
    int js[4] = {d.x, d.y, d.z, d.w};
#pragma unroll
    for (int m = 0; m < 4; ++m) {
      int j = js[m];
      if (j >= lo && j < hi && ((lm[j >> 5] >> (j & 31)) & 1u)) s = true;
    }
  }
  return s;
}

__global__ __launch_bounds__(BLK) void nms_chain_kernel(
    const int* __restrict__ knn,
    int* __restrict__ out,
    unsigned int* __restrict__ progress)
{
  const int b    = blockIdx.x;
  const int t    = threadIdx.x;
  const int base = b * CHUNK;
  const int winb = (b > WCH) ? (base - WCH * CHUNK) : 0;   // exl window base

  unsigned long long* bmg64 = (unsigned long long*)(out + BMG_INT_OFF);

  __shared__ unsigned char      st[CHUNK];        // 0 unk, 1 kept, 2 supp
  __shared__ unsigned short     il[ICAP][CHUNK];  // TRANSPOSED staging (writes)
  __shared__ unsigned short     exl[ECAP][CHUNK]; // TRANSPOSED: conflict-free
  __shared__ unsigned int       lm[LMW];          // mirrored keep bits
  __shared__ unsigned long long bw[QRT][BLK / 64];
  __shared__ unsigned int       sh_p;
  __shared__ int                flags[2];

  int  rowq[QRT];
  bool vq[QRT], ovf[QRT], eovf[QRT], supp[QRT];
  int  ic[QRT], ec[QRT];

#pragma unroll
  for (int q = 0; q < QRT; ++q) {
    rowq[q] = base + q * BLK + t;
    vq[q]   = rowq[q] < M_ROWS;
    ic[q] = ec[q] = 0;
    ovf[q] = eovf[q] = supp[q] = false;
  }

  // ---- classification: intra-chunk + static-window pred lists ----
#pragma unroll
  for (int q = 0; q < QRT; ++q) {
    if (!vq[q]) continue;
    const int o   = q * BLK + t;
    const int row = rowq[q];
    const int* rp = knn + (long long)row * KNN;
#pragma unroll
    for (int u = 0; u < 16; ++u) {
      int4 d = ((const int4*)rp)[u];
      int js[4] = {d.x, d.y, d.z, d.w};
#pragma unroll
      for (int m = 0; m < 4; ++m) {
        int j = js[m];
        if (j < row) {                            // strict <: ref semantics
          if (j >= base) {
            if (ic[q] < ICAP) il[ic[q]][o] = (unsigned short)(j - base);
            ++ic[q];
          } else if (j >= winb) {
            if (ec[q] < ECAP) exl[ec[q]][o] = (unsigned short)(j - winb);
            ++ec[q];
          }
          // j < winb: covered by the phase-1 reload probe
        }
      }
    }
  }
#pragma unroll
  for (int q = 0; q < QRT; ++q) {
    ovf[q]  = ic[q] > ICAP; if (ovf[q])  ic[q] = ICAP;
    eovf[q] = ec[q] > ECAP; if (eovf[q]) ec[q] = ECAP;
  }

  // ---- pre-wait: read il lists back into registers (own writes; no barrier;
  //      full unroll -> compile-time indices -> stays in VGPRs) ----
  unsigned short ilr[QRT][ICAP];
#pragma unroll
  for (int q = 0; q < QRT; ++q)
#pragma unroll
    for (int x = 0; x < ICAP; ++x)
      ilr[q][x] = il[x][q * BLK + t];             // garbage beyond ic[q]: never used

  // ---- wait path ----
  int praw1 = 0, wcop = 0;
  if (b > WCH) {
    // phase 1: counter is only a trigger hint for the single forced reload
    if (t < 64) {
      int pr = 0;
      for (int spin = 0; spin < (1 << 22); ++spin) {
        pr = (int)__hip_atomic_load(progress, __ATOMIC_RELAXED,
                                    __HIP_MEMORY_SCOPE_AGENT);
        if (pr >= b - WCH) break;
        __builtin_amdgcn_s_sleep(2);
      }
      if (t == 0) sh_p = (unsigned int)pr;
    }
    __syncthreads();                              // sh_p visible
    praw1 = (int)sh_p; if (praw1 > b) praw1 = b;
    const int wt = praw1 * W64PC;
    for (int w = t; w < wt; w += BLK) {           // per-word valid-spin backstop
      unsigned long long v = __hip_atomic_load(&bmg64[w], __ATOMIC_RELAXED,
                                               __HIP_MEMORY_SCOPE_AGENT);
      int g1 = 0;
      while (!(v & VALIDB) && ++g1 < (1 << 22)) {
        __builtin_amdgcn_s_sleep(1);
        v = __hip_atomic_load(&bmg64[w], __ATOMIC_RELAXED,
                              __HIP_MEMORY_SCOPE_AGENT);
      }
      lm[w] = (unsigned int)v;
    }
    wcop = wt;
    __syncthreads();                              // lm visible
    const int lim = praw1 * CHUNK;
#pragma unroll
    for (int q = 0; q < QRT; ++q)
      if (vq[q])
        supp[q] = probe_reload(knn + (long long)rowq[q] * KNN, lm, 0, lim);
  }
  // phase 2: turn-wait == data arrival. Spin directly on predecessor words
  // (<= ~256 words -> waves 0-3 spin, waves 4-15 park at the barrier).
  if (b > 0 && wcop < b * W64PC) {
    const int wt = b * W64PC;
    for (int w = wcop + t; w < wt; w += BLK) {
      unsigned long long v = __hip_atomic_load(&bmg64[w], __ATOMIC_RELAXED,
                                               __HIP_MEMORY_SCOPE_AGENT);
      int g2 = 0;
      while (!(v & VALIDB) && ++g2 < (1 << 22)) {
        __builtin_amdgcn_s_sleep(1);
        v = __hip_atomic_load(&bmg64[w], __ATOMIC_RELAXED,
                              __HIP_MEMORY_SCOPE_AGENT);
      }
      lm[w] = (unsigned int)v;
    }
    __syncthreads();                              // lm complete
  }
  if (b > 0) {
    // window probes, unrolled + predicated (no break): loads pipeline
    const int pr1lim = praw1 * CHUNK;
#pragma unroll
    for (int q = 0; q < QRT; ++q) {
      if (!vq[q] || supp[q]) continue;
      const int o = q * BLK + t;
      const int n = ec[q];
      bool s = false;
#pragma unroll
      for (int x = 0; x < ECAP; ++x) {
        if (x < n) {
          int j = winb + (int)exl[x][o];
          s |= (j >= pr1lim) && (((lm[j >> 5] >> (j & 31)) & 1u) != 0u);
        }
      }
      if (s) supp[q] = true;
      if (!supp[q] && eovf[q])                    // dropped entries (rare)
        supp[q] = probe_reload(knn + (long long)rowq[q] * KNN, lm, winb, base);
    }
  }

  // ---- intra-chunk monotone fixed-point: ONE barrier per iteration ----
#pragma unroll
  for (int q = 0; q < QRT; ++q) {
    const int o = q * BLK + t;
    st[o] = (!vq[q] || supp[q]) ? (unsigned char)2
          : ((ic[q] == 0 && !ovf[q]) ? (unsigned char)1 : (unsigned char)0);
  }
  if (t == 0) { flags[0] = 0; flags[1] = 0; }
  __syncthreads();

  for (int it = 0; it < CHUNK; ++it) {
    bool un = false;
#pragma unroll
    for (int s = 0; s < 3; ++s) {                 // monotone: stale reads safe
      un = false;
#pragma unroll
      for (int q = 0; q < QRT; ++q) {
        const int o = q * BLK + t;
        if (st[o] == 0) {
          bool anyK = false, allD = true;
          if (!ovf[q]) {
#pragma unroll
            for (int x = 0; x < ICAP; ++x) {      // single-level LDS: st[reg]
              if (x < ic[q]) {
                unsigned char v = st[ilr[q][x]];
                anyK |= (v == 1); allD &= (v != 0);
              }
            }
          } else {                                // rare: rescan from global
            const int row = rowq[q];
            const int* rp = knn + (long long)row * KNN;
#pragma unroll
            for (int k = 0; k < KNN; ++k) {
              int j = rp[k];
              if (j >= base && j < row) {
                unsigned char v = st[j - base];
                anyK |= (v == 1); allD &= (v != 0);
              }
            }
          }
          if (anyK) st[o] = 2; else if (allD) st[o] = 1;
          if (st[o] == 0) un = true;
        }
      }
    }
    if (t == 0) flags[(it + 1) & 1] = 0;          // pre-zero next slot
    if (un) flags[it & 1] = 1;                    // benign race
    __syncthreads();                              // st + flags visible
    if (flags[it & 1] == 0) break;
  }

  // ---- publish: ballots -> LDS -> wave 0 stores u64 words w/ valid bit ----
  bool kq[QRT];
#pragma unroll
  for (int q = 0; q < QRT; ++q)
    kq[q] = vq[q] && (st[q * BLK + t] == 1);

#pragma unroll
  for (int q = 0; q < QRT; ++q) {
    unsigned long long ba = __ballot(kq[q]);      // rows base+q*1024+w*64+lane
    if ((t & 63) == 0) bw[q][t >> 6] = ba;
  }
  __syncthreads();
  if (b < NCH - 1 && t < W64PC) {                 // wave 0: 64 u64 words
    const int g = t;                              // rows g*32 .. g*32+31
    const unsigned long long full = bw[g >> 5][(g & 31) >> 1];
    unsigned long long val = (g & 1) ? (full >> 32) : (full & 0xffffffffull);
    __hip_atomic_store(&bmg64[b * W64PC + g], val | VALIDB,
                       __ATOMIC_RELAXED, __HIP_MEMORY_SCOPE_AGENT);
  }
  if (t == 0)                                     // hint only; relaxed is fine
    __hip_atomic_store(progress, (unsigned int)(b + 1),
                       __ATOMIC_RELAXED, __HIP_MEMORY_SCOPE_AGENT);

  // ---- outputs (off the chain; block 73's knn overwrites dead scratch) ----
#pragma unroll
  for (int q = 0; q < QRT; ++q)
    if (vq[q]) out[rowq[q]] = kq[q] ? 1 : 0;

#pragma unroll
  for (int q = 0; q < QRT; ++q) {
    if (!vq[q]) continue;
    const int row = rowq[q];
    const int* rp = knn + (long long)row * KNN;
    int* orow = out + M_ROWS + (long long)row * KNN;
    const bool k = kq[q];
#pragma unroll
    for (int u = 0; u < 16; ++u) {
      int4 d = ((const int4*)rp)[u];
      int4 o4;
      o4.x = k ? d.x : M_ROWS;
      o4.y = k ? d.y : M_ROWS;
      o4.z = k ? d.z : M_ROWS;
      o4.w = k ? d.w : M_ROWS;
      ((int4*)orow)[u] = o4;
    }
  }
}

extern "C" void kernel_launch(void* const* d_in, const int* in_sizes, int n_in,
                              void* d_out, int out_size, void* d_ws, size_t ws_size,
                              hipStream_t stream) {
  const int* knn = (const int*)d_in[1];
  int* out = (int*)d_out;
  unsigned int* progress = (unsigned int*)d_ws;

  init_ws_kernel<<<(NBMG + BLK - 1) / BLK, BLK, 0, stream>>>(progress, out);
  nms_chain_kernel<<<NCH, BLK, 0, stream>>>(knn, out, progress);
}